// Round 1
// baseline (563.410 us; speedup 1.0000x reference)
//
#include <hip/hip_runtime.h>
#include <math.h>

#define NPTS 400000
#define K27  27
#define LDT  72        // LDS row stride in shorts (144 B: 16B-aligned, breaks 128B bank stride)

typedef unsigned short u16;
typedef __bf16 bf16x8 __attribute__((ext_vector_type(8)));
typedef float  f32x4  __attribute__((ext_vector_type(4)));

__device__ __forceinline__ u16 f2bf(float f) {
    unsigned u = __float_as_uint(f);
    u += 0x7FFFu + ((u >> 16) & 1u);   // RNE round to bf16
    return (u16)(u >> 16);
}
__device__ __forceinline__ unsigned pack2(float lo, float hi) {
    return (unsigned)f2bf(lo) | ((unsigned)f2bf(hi) << 16);
}

// ---------------------------------------------------------------------------
// prep: transpose+pad W1 [27][64][38] -> W1t [27][48][64] bf16 (n-major, k-contig)
//       and W2 [27][38][38] -> W2t [27][48][64] bf16, zero-padded
// ---------------------------------------------------------------------------
__global__ void prep_w(const float* __restrict__ W1, const float* __restrict__ W2,
                       u16* __restrict__ W1t, u16* __restrict__ W2t)
{
    int i = blockIdx.x * 256 + threadIdx.x;
    const int TOT = K27 * 48 * 64;
    if (i >= TOT) return;
    int k  = i / (48 * 64);
    int r  = i % (48 * 64);
    int n  = r >> 6;    // 0..47 (out channel)
    int kc = r & 63;    // 0..63 (in channel)
    u16 w1 = 0, w2 = 0;
    if (n < 38) {
        w1 = f2bf(W1[(k * 64 + kc) * 38 + n]);
        if (kc < 38) w2 = f2bf(W2[(k * 38 + kc) * 38 + n]);
    }
    W1t[i] = w1;
    W2t[i] = w2;
}

// ---------------------------------------------------------------------------
// prep: features fp32 [N][64] -> bf16 [N][64]  (8 elems / thread)
// ---------------------------------------------------------------------------
__global__ void prep_feat(const float* __restrict__ F, u16* __restrict__ Fb)
{
    size_t i = (size_t)blockIdx.x * 256 + threadIdx.x;     // chunk of 8 elems
    const size_t TOT = (size_t)NPTS * 64 / 8;              // 3,200,000 exact
    if (i >= TOT) return;
    const float4* fp = (const float4*)(F + i * 8);
    float4 a = fp[0], b = fp[1];
    uint4 v;
    v.x = pack2(a.x, a.y); v.y = pack2(a.z, a.w);
    v.z = pack2(b.x, b.y); v.w = pack2(b.z, b.w);
    *(uint4*)(Fb + i * 8) = v;
}

// ---------------------------------------------------------------------------
// gather-GEMM layer. 1 block = 64 points x 48 (padded) out channels.
// LAYER==1: input rows (fp32 or bf16) -> GELU -> h bf16 [N][64] (cols>=38 zero)
// LAYER==2: input h bf16 [N][64]      -> fp32 out [N][38]
// ---------------------------------------------------------------------------
template<int LAYER, bool BF16IN>
__global__ __launch_bounds__(256)
void spconv(const void* __restrict__ in_, const int* __restrict__ nbr,
            const u16* __restrict__ Wt, void* __restrict__ out_)
{
    __shared__ __align__(16) u16 As[64 * LDT];   //  9,216 B
    __shared__ __align__(16) u16 Ws[48 * LDT];   //  6,912 B

    const int t    = threadIdx.x;
    const int wave = t >> 6;
    const int lane = t & 63;
    const int quad = lane >> 4;
    const int l16  = lane & 15;
    const int base = blockIdx.x * 64;            // 6250 * 64 == 400000 exact

    f32x4 acc[3] = {};                           // 3 n-tiles of 16 cols

    for (int k = 0; k < K27; ++k) {
        // ---- stage W[k]t : 48 rows x 64 shorts = 384 x 16B chunks ----
        {
            const uint4* wg = (const uint4*)(Wt + (size_t)k * 48 * 64);
            uint4 v = wg[t];
            *(uint4*)&Ws[(t >> 3) * LDT + (t & 7) * 8] = v;
            if (t < 128) {
                int c = t + 256;
                uint4 v2 = wg[c];
                *(uint4*)&Ws[(c >> 3) * LDT + (c & 7) * 8] = v2;
            }
        }
        // ---- gather A tile: 64 rows x 64 ch, 512 x 16B chunks ----
        {
            const int* nrow = nbr + (size_t)k * NPTS + base;
            #pragma unroll
            for (int rep = 0; rep < 2; ++rep) {
                int c    = t + rep * 256;
                int row  = c >> 3;
                int colc = (c & 7) * 8;
                int idx  = nrow[row];
                uint4 v;
                if (idx < NPTS) {
                    if (BF16IN) {
                        v = *(const uint4*)((const u16*)in_ + (size_t)idx * 64 + colc);
                    } else {
                        const float4* fp = (const float4*)((const float*)in_ + (size_t)idx * 64 + colc);
                        float4 f0 = fp[0], f1 = fp[1];
                        v.x = pack2(f0.x, f0.y); v.y = pack2(f0.z, f0.w);
                        v.z = pack2(f1.x, f1.y); v.w = pack2(f1.z, f1.w);
                    }
                } else {
                    v.x = 0; v.y = 0; v.z = 0; v.w = 0;
                }
                *(uint4*)&As[row * LDT + colc] = v;
            }
        }
        __syncthreads();
        // ---- MFMA: wave owns rows [wave*16, wave*16+16) ----
        #pragma unroll
        for (int ks = 0; ks < 2; ++ks) {
            bf16x8 a = *(const bf16x8*)&As[(wave * 16 + l16) * LDT + ks * 32 + quad * 8];
            #pragma unroll
            for (int nt = 0; nt < 3; ++nt) {
                bf16x8 b = *(const bf16x8*)&Ws[(nt * 16 + l16) * LDT + ks * 32 + quad * 8];
                acc[nt] = __builtin_amdgcn_mfma_f32_16x16x32_bf16(a, b, acc[nt], 0, 0, 0);
            }
        }
        __syncthreads();
    }

    // ---- epilogue ----
    if (LAYER == 1) {
        u16* h = (u16*)out_;
        #pragma unroll
        for (int nt = 0; nt < 3; ++nt) {
            #pragma unroll
            for (int r = 0; r < 4; ++r) {
                int row = base + wave * 16 + quad * 4 + r;
                int col = nt * 16 + l16;
                float x = acc[nt][r];
                float g = 0.5f * x * (1.0f + erff(x * 0.70710678118654752f));
                h[(size_t)row * 64 + col] = f2bf(g);
            }
        }
        #pragma unroll
        for (int r = 0; r < 4; ++r) {          // zero pad cols 48..63
            int row = base + wave * 16 + quad * 4 + r;
            h[(size_t)row * 64 + 48 + l16] = 0;
        }
    } else {
        float* out = (float*)out_;
        #pragma unroll
        for (int nt = 0; nt < 3; ++nt) {
            int col = nt * 16 + l16;
            if (col < 38) {
                #pragma unroll
                for (int r = 0; r < 4; ++r) {
                    int row = base + wave * 16 + quad * 4 + r;
                    out[(size_t)row * 38 + col] = acc[nt][r];
                }
            }
        }
    }
}

// ---------------------------------------------------------------------------
extern "C" void kernel_launch(void* const* d_in, const int* in_sizes, int n_in,
                              void* d_out, int out_size, void* d_ws, size_t ws_size,
                              hipStream_t stream)
{
    const float* feat = (const float*)d_in[0];   // [N][64] fp32
    const int*   nbr  = (const int*)  d_in[1];   // [27][N] int32, N == pad idx
    const float* W1   = (const float*)d_in[2];   // [27][64][38]
    const float* W2   = (const float*)d_in[3];   // [27][38][38]

    const size_t hbytes = (size_t)NPTS * 64 * 2;     // 51,200,000
    const size_t wbytes = (size_t)K27 * 48 * 64 * 2; // 165,888

    char* ws  = (char*)d_ws;
    u16* h    = (u16*)ws;
    u16* W1t  = (u16*)(ws + hbytes);
    u16* W2t  = (u16*)(ws + hbytes + wbytes);
    u16* Fb   = (u16*)(ws + hbytes + 2 * wbytes);
    const bool full = ws_size >= hbytes * 2 + 2 * wbytes;   // bf16 feature copy fits?

    prep_w<<<(K27 * 48 * 64 + 255) / 256, 256, 0, stream>>>(W1, W2, W1t, W2t);

    const int nblk = NPTS / 64;   // 6250, exact
    if (full) {
        prep_feat<<<(int)(((size_t)NPTS * 64 / 8 + 255) / 256), 256, 0, stream>>>(feat, Fb);
        spconv<1, true ><<<nblk, 256, 0, stream>>>(Fb,   nbr, W1t, h);
    } else {
        spconv<1, false><<<nblk, 256, 0, stream>>>(feat, nbr, W1t, h);
    }
    spconv<2, true ><<<nblk, 256, 0, stream>>>(h, nbr, W2t, d_out);
}